// Round 9
// baseline (83.078 us; speedup 1.0000x reference)
//
#include <hip/hip_runtime.h>

#define B_ 64
#define N_ 2048
#define J_ 32
#define D_ 128
#define NEG_SLOPE_ 0.2f

typedef __attribute__((ext_vector_type(4))) float f32x4;
typedef __attribute__((ext_vector_type(8))) __bf16 bf16x8;
typedef __attribute__((ext_vector_type(4))) __bf16 bf16x4;

#define ACT_NONE 0
#define ACT_ELU 1
#define ACT_LEAKY 2

template<int ACT>
__device__ __forceinline__ float apply_act(float v) {
    if constexpr (ACT == ACT_ELU)        return v > 0.f ? v : __expf(v) - 1.f;
    else if constexpr (ACT == ACT_LEAKY) return v >= 0.f ? v : NEG_SLOPE_ * v;
    else return v;
}

// read one bf16x8 fragment from swizzled row-major [row][128] storage
__device__ __forceinline__ bf16x8 frag_ld(const __bf16* src, int row, int kc) {
    return *(const bf16x8*)&src[row * D_ + ((kc ^ (row & 7)) << 3)];
}

// preload this wave's 32-col W^T strip into registers: 8 frags (32 VGPR)
__device__ __forceinline__ void load_wregs2(const __bf16* __restrict__ wmat,
                                            int wst, int ln, int lq, bf16x8 wr_[4][2]) {
#pragma unroll
    for (int ks = 0; ks < 4; ++ks)
#pragma unroll
        for (int mt = 0; mt < 2; ++mt)
            wr_[ks][mt] = frag_ld(wmat, wst * 32 + mt * 16 + ln, ks * 4 + lq);
}

// strip GEMM: 64 LDS rows @ W^T strip (regs).
// lane holds out[row = nt*16 + (l&15)][cols = wst*32 + mt*16 + lq*4 .. +3]
__device__ __forceinline__ void gemmS(const __bf16* xb, const bf16x8 wr_[4][2],
                                      int ln, int lq, f32x4 acc[2][4]) {
    const f32x4 z = {0.f, 0.f, 0.f, 0.f};
#pragma unroll
    for (int mt = 0; mt < 2; ++mt)
#pragma unroll
        for (int nt = 0; nt < 4; ++nt) acc[mt][nt] = z;
#pragma unroll
    for (int ks = 0; ks < 4; ++ks) {
        const int kc = ks * 4 + lq;
        bf16x8 b[4];
#pragma unroll
        for (int nt = 0; nt < 4; ++nt) b[nt] = frag_ld(xb, nt * 16 + ln, kc);
#pragma unroll
        for (int mt = 0; mt < 2; ++mt)
#pragma unroll
            for (int nt = 0; nt < 4; ++nt)
                acc[mt][nt] = __builtin_amdgcn_mfma_f32_16x16x32_bf16(wr_[ks][mt], b[nt], acc[mt][nt], 0, 0, 0);
    }
}

// strip epilogue: act(acc + bias) -> swizzled LDS rows, bf16x4 per store
template<int ACT>
__device__ __forceinline__ void epiS_lds(const f32x4 acc[2][4], __bf16* dst,
                                         const float* __restrict__ bias,
                                         int wst, int ln, int lq) {
#pragma unroll
    for (int mt = 0; mt < 2; ++mt) {
        const int cb = wst * 32 + mt * 16 + lq * 4;
        const f32x4 bv = *(const f32x4*)&bias[cb];
#pragma unroll
        for (int nt = 0; nt < 4; ++nt) {
            const int jr = nt * 16 + ln;
            bf16x4 o;
#pragma unroll
            for (int r = 0; r < 4; ++r)
                o[r] = (__bf16)apply_act<ACT>(acc[mt][nt][r] + bv[r]);
            *(bf16x4*)&dst[jr * D_ + (((cb >> 3) ^ (jr & 7)) << 3) + (cb & 7)] = o;
        }
    }
}

// prep: blocks 0-5 convert W fp32 -> WT bf16 swizzled; blocks 6-69 Sbuf + nvalid
__global__ __launch_bounds__(256) void k_prep(
    const float* __restrict__ w0, const float* __restrict__ w1,
    const float* __restrict__ w2, const float* __restrict__ w3,
    const float* __restrict__ w4, const float* __restrict__ w5,
    __bf16* __restrict__ wdst,
    const float* __restrict__ F, const int* __restrict__ STEP,
    const int* __restrict__ ENDB, const int* __restrict__ BIDX,
    float* __restrict__ Sbuf, int* __restrict__ nvalid) {
    const int t = threadIdx.x;
    if (blockIdx.x < 6) {
        const float* src;
        switch (blockIdx.x) {
            case 0: src = w0; break; case 1: src = w1; break; case 2: src = w2; break;
            case 3: src = w3; break; case 4: src = w4; break; default: src = w5; break;
        }
        __bf16* d = wdst + (size_t)blockIdx.x * D_ * D_;
        for (int id = t; id < D_ * 16; id += 256) {
            const int n = id >> 4, ch = id & 15;
            bf16x8 u;
#pragma unroll
            for (int j = 0; j < 8; ++j) u[j] = (__bf16)src[(ch * 8 + j) * D_ + n];
            *(bf16x8*)&d[n * D_ + ((ch ^ (n & 7)) << 3)] = u;
        }
        return;
    }
    const int b = blockIdx.x - 6;
    __shared__ int steps_s[J_];
    __shared__ int valid_s[J_];
    __shared__ int nv;
    const int bi = BIDX[b];
    if (t == 0) nv = 0;
    __syncthreads();
    if (t < J_) {
        const int s = STEP[bi * J_ + t];
        const int e = ENDB[bi * J_ + t];
        steps_s[t] = s;
        const int v = (s <= e) ? 1 : 0;
        valid_s[t] = v;
        if (v) atomicAdd(&nv, 1);
    }
    __syncthreads();
    if (t < D_) {
        float acc = 0.f;
        for (int j = 0; j < J_; ++j)
            if (valid_s[j]) acc += F[((size_t)b * N_ + steps_s[j]) * D_ + t];
        Sbuf[b * D_ + t] = acc;
    }
    if (t == 0) nvalid[b] = nv;
}

// fully fused: one 64-row output slot per block.
// cat: 0 = passthrough (x), 1 = updated (cand via fw MLP), 2 = valid head (z via zj MLP)
__global__ __launch_bounds__(256, 2) void k_fused(
    const float* __restrict__ F, const float* __restrict__ rp_,
    const __bf16* __restrict__ wsW,
    const float* __restrict__ fb1, const float* __restrict__ fb2,
    const float* __restrict__ zb1, const float* __restrict__ zb2,
    const float* __restrict__ pb1, const float* __restrict__ pb2,
    const int* __restrict__ STEP, const int* __restrict__ ENDB,
    const int* __restrict__ BIDX, const float* __restrict__ Sbuf,
    const int* __restrict__ nvalid, float* __restrict__ out) {
    __shared__ __bf16 xs[128 * D_];
    __shared__ __bf16 hs[128 * D_];
    __shared__ int stj[J_];
    __shared__ int ens[J_];
    __shared__ unsigned char cat[64];
    __shared__ float rsc_s[64];

    const int t = threadIdx.x;
    const int lane = t & 63, wst = t >> 6;
    const int ln = lane & 15, lq = lane >> 4;
    const int bid = blockIdx.x;
    const int b = bid >> 5, ti = bid & 31;
    const int r0 = ti * 64;
    const int bi = BIDX[b];
    if (t < J_) { stj[t] = STEP[bi * J_ + t]; ens[t] = ENDB[bi * J_ + t]; }
    __syncthreads();
    const float r = *rp_;
    if (t < 64) {
        const int i = r0 + t;
        const int j = i >> 6;
        const bool head = (i < J_) && (stj[i] <= ens[i]);
        const bool upd = (i > stj[j]) && (i <= ens[j]);
        const unsigned char c = head ? 2 : (upd ? 1 : 0);
        cat[t] = c;
        rsc_s[t] = (c == 1) ? __powf(r, (float)(i - stj[j])) : 0.f;
    }
    __syncthreads();

    // stage: xs rows 0-63 = x; rows 64-127 = updated ? x_prev * r^k : 0
    const float* Fb = F + (size_t)b * N_ * D_;
    for (int id = t; id < 128 * 16; id += 256) {
        const int rr = id >> 4, ch = id & 15;
        bf16x8 u;
        if (rr < 64) {
            const float* fr = Fb + (size_t)(r0 + rr) * D_ + ch * 8;
            const float4 f0 = *(const float4*)fr, f1 = *(const float4*)(fr + 4);
            u[0] = (__bf16)f0.x; u[1] = (__bf16)f0.y; u[2] = (__bf16)f0.z; u[3] = (__bf16)f0.w;
            u[4] = (__bf16)f1.x; u[5] = (__bf16)f1.y; u[6] = (__bf16)f1.z; u[7] = (__bf16)f1.w;
        } else {
            const int lr = rr - 64;
            if (cat[lr] == 1) {
                const float s = rsc_s[lr];
                const float* fr = Fb + (size_t)(r0 + lr - 1) * D_ + ch * 8;
                const float4 f0 = *(const float4*)fr, f1 = *(const float4*)(fr + 4);
                u[0] = (__bf16)(f0.x * s); u[1] = (__bf16)(f0.y * s);
                u[2] = (__bf16)(f0.z * s); u[3] = (__bf16)(f0.w * s);
                u[4] = (__bf16)(f1.x * s); u[5] = (__bf16)(f1.y * s);
                u[6] = (__bf16)(f1.z * s); u[7] = (__bf16)(f1.w * s);
            } else {
#pragma unroll
                for (int j = 0; j < 8; ++j) u[j] = (__bf16)0.f;
            }
        }
        *(bf16x8*)&xs[rr * D_ + ((ch ^ (rr & 7)) << 3)] = u;
    }
    __syncthreads();

    // fw layer 1: both branches (128 rows) -> hs
    {
        bf16x8 w1r[4][2];
        load_wregs2(wsW, wst, ln, lq, w1r);                   // fw W1^T strip
        f32x4 acc[2][4];
        gemmS(xs, w1r, ln, lq, acc);
        epiS_lds<ACT_ELU>(acc, hs, fb1, wst, ln, lq);
        gemmS(xs + 64 * D_, w1r, ln, lq, acc);
        epiS_lds<ACT_ELU>(acc, hs + 64 * D_, fb1, wst, ln, lq);
    }
    __syncthreads();

    // fw layer 2, chained over both branches; cand -> xs (predicated cat==1)
    {
        bf16x8 w2r[4][2];
        load_wregs2(wsW + 16384, wst, ln, lq, w2r);           // fw W2^T strip
        f32x4 a2[2][4];
        const f32x4 z = {0.f, 0.f, 0.f, 0.f};
#pragma unroll
        for (int mt = 0; mt < 2; ++mt)
#pragma unroll
            for (int nt = 0; nt < 4; ++nt) a2[mt][nt] = z;
#pragma unroll
        for (int ks = 0; ks < 4; ++ks) {
            const int kc = ks * 4 + lq;
#pragma unroll
            for (int nt = 0; nt < 4; ++nt) {
                const bf16x8 bl = frag_ld(hs, nt * 16 + ln, kc);
                const bf16x8 bh = frag_ld(hs, 64 + nt * 16 + ln, kc);
#pragma unroll
                for (int mt = 0; mt < 2; ++mt) {
                    a2[mt][nt] = __builtin_amdgcn_mfma_f32_16x16x32_bf16(w2r[ks][mt], bl, a2[mt][nt], 0, 0, 0);
                    a2[mt][nt] = __builtin_amdgcn_mfma_f32_16x16x32_bf16(w2r[ks][mt], bh, a2[mt][nt], 0, 0, 0);
                }
            }
        }
#pragma unroll
        for (int nt = 0; nt < 4; ++nt) {
            const int row = nt * 16 + ln;
            if (cat[row] != 1) continue;
#pragma unroll
            for (int mt = 0; mt < 2; ++mt) {
                const int cb = wst * 32 + mt * 16 + lq * 4;
                const f32x4 bv = *(const f32x4*)&fb2[cb];
                bf16x4 o;
#pragma unroll
                for (int rr2 = 0; rr2 < 4; ++rr2)
                    o[rr2] = (__bf16)(a2[mt][nt][rr2] + 2.f * bv[rr2]);
                *(bf16x4*)&xs[row * D_ + (((cb >> 3) ^ (row & 7)) << 3) + (cb & 7)] = o;
            }
        }
    }

    // head path (slot 0 only): z = MLP_zj(mixed) -> xs (predicated cat==2)
    if (ti == 0) {
        __syncthreads();   // all hs reads from fw layer 2 done
        const float n_ = (float)nvalid[b];
        const float inv = (n_ > 0.f) ? 1.f / n_ : 0.f;
        for (int id = t; id < 32 * 16; id += 256) {
            const int row = id >> 4, ch = id & 15;
            bf16x8 u;
            if (cat[row] == 2) {
                const float* cr = Fb + (size_t)stj[row] * D_ + ch * 8;
                const float4 c0 = *(const float4*)cr, c1 = *(const float4*)(cr + 4);
                const float4 s0 = *(const float4*)(Sbuf + b * D_ + ch * 8);
                const float4 s1 = *(const float4*)(Sbuf + b * D_ + ch * 8 + 4);
                u[0] = (__bf16)((c0.x + r * (s0.x - c0.x)) * inv);
                u[1] = (__bf16)((c0.y + r * (s0.y - c0.y)) * inv);
                u[2] = (__bf16)((c0.z + r * (s0.z - c0.z)) * inv);
                u[3] = (__bf16)((c0.w + r * (s0.w - c0.w)) * inv);
                u[4] = (__bf16)((c1.x + r * (s1.x - c1.x)) * inv);
                u[5] = (__bf16)((c1.y + r * (s1.y - c1.y)) * inv);
                u[6] = (__bf16)((c1.z + r * (s1.z - c1.z)) * inv);
                u[7] = (__bf16)((c1.w + r * (s1.w - c1.w)) * inv);
            } else {
#pragma unroll
                for (int j = 0; j < 8; ++j) u[j] = (__bf16)0.f;
            }
            *(bf16x8*)&hs[row * D_ + ((ch ^ (row & 7)) << 3)] = u;
        }
        __syncthreads();
        f32x4 az[2][4];
        {
            bf16x8 wza[4][2];
            load_wregs2(wsW + 4 * 16384, wst, ln, lq, wza);   // zj W1^T strip
            gemmS(hs, wza, ln, lq, az);                       // rows 32-63 garbage, discarded
            epiS_lds<ACT_ELU>(az, hs + 64 * D_, zb1, wst, ln, lq);
        }
        __syncthreads();
        {
            bf16x8 wzb[4][2];
            load_wregs2(wsW + 5 * 16384, wst, ln, lq, wzb);   // zj W2^T strip
            gemmS(hs + 64 * D_, wzb, ln, lq, az);
#pragma unroll
            for (int nt = 0; nt < 4; ++nt) {
                const int row = nt * 16 + ln;
                if (cat[row] != 2) continue;
#pragma unroll
                for (int mt = 0; mt < 2; ++mt) {
                    const int cb = wst * 32 + mt * 16 + lq * 4;
                    const f32x4 bv = *(const f32x4*)&zb2[cb];
                    bf16x4 o;
#pragma unroll
                    for (int rr2 = 0; rr2 < 4; ++rr2)
                        o[rr2] = (__bf16)(az[mt][nt][rr2] + bv[rr2]);
                    *(bf16x4*)&xs[row * D_ + (((cb >> 3) ^ (row & 7)) << 3) + (cb & 7)] = o;
                }
            }
        }
    }
    __syncthreads();   // xs finalized (x / cand / z); hs free

    // pr MLP on xs rows 0-63 -> out
    f32x4 ap[2][4];
    {
        bf16x8 p1r[4][2];
        load_wregs2(wsW + 2 * 16384, wst, ln, lq, p1r);       // pr W1^T strip
        gemmS(xs, p1r, ln, lq, ap);
        epiS_lds<ACT_ELU>(ap, hs, pb1, wst, ln, lq);
    }
    __syncthreads();
    {
        bf16x8 p2r[4][2];
        load_wregs2(wsW + 3 * 16384, wst, ln, lq, p2r);       // pr W2^T strip
        gemmS(hs, p2r, ln, lq, ap);
        float* outb = out + ((size_t)b * N_ + r0) * D_;
#pragma unroll
        for (int mt = 0; mt < 2; ++mt) {
            const int cb = wst * 32 + mt * 16 + lq * 4;
            const f32x4 bv = *(const f32x4*)&pb2[cb];
#pragma unroll
            for (int nt = 0; nt < 4; ++nt) {
                const int jr = nt * 16 + ln;
                f32x4 o;
#pragma unroll
                for (int rr2 = 0; rr2 < 4; ++rr2)
                    o[rr2] = apply_act<ACT_LEAKY>(ap[mt][nt][rr2] + bv[rr2]);
                *(f32x4*)&outb[(size_t)jr * D_ + cb] = o;
            }
        }
    }
}

extern "C" void kernel_launch(void* const* d_in, const int* in_sizes, int n_in,
                              void* d_out, int out_size, void* d_ws, size_t ws_size,
                              hipStream_t stream) {
    const float* F    = (const float*)d_in[0];
    const float* rp   = (const float*)d_in[1];
    const int*  STEP  = (const int*)d_in[2];
    const int*  ENDB  = (const int*)d_in[3];
    const int*  BIDX  = (const int*)d_in[5];
    const float* fwW1 = (const float*)d_in[6];
    const float* fwb1 = (const float*)d_in[7];
    const float* fwW2 = (const float*)d_in[8];
    const float* fwb2 = (const float*)d_in[9];
    const float* zjW1 = (const float*)d_in[10];
    const float* zjb1 = (const float*)d_in[11];
    const float* zjW2 = (const float*)d_in[12];
    const float* zjb2 = (const float*)d_in[13];
    const float* prW1 = (const float*)d_in[14];
    const float* prb1 = (const float*)d_in[15];
    const float* prW2 = (const float*)d_in[16];
    const float* prb2 = (const float*)d_in[17];
    float* out = (float*)d_out;

    char* ws = (char*)d_ws;
    __bf16* wsW = (__bf16*)ws;                 // 393216 B
    float* Sbuf = (float*)(ws + 393216);       // 32768 B
    int* nvalid = (int*)(ws + 425984);         // 256 B

    hipLaunchKernelGGL(k_prep, dim3(70), dim3(256), 0, stream,
                       fwW1, fwW2, prW1, prW2, zjW1, zjW2, wsW,
                       F, STEP, ENDB, BIDX, Sbuf, nvalid);
    hipLaunchKernelGGL(k_fused, dim3(B_ * 32), dim3(256), 0, stream,
                       F, rp, wsW, fwb1, fwb2, zjb1, zjb2, prb1, prb2,
                       STEP, ENDB, BIDX, Sbuf, nvalid, out);
}

// Round 10
// 72.769 us; speedup vs baseline: 1.1417x; 1.1417x over previous
//
#include <hip/hip_runtime.h>

#define B_ 64
#define N_ 2048
#define J_ 32
#define D_ 128
#define NEG_SLOPE_ 0.2f

typedef __attribute__((ext_vector_type(4))) float f32x4;
typedef __attribute__((ext_vector_type(8))) __bf16 bf16x8;
typedef __attribute__((ext_vector_type(4))) __bf16 bf16x4;

#define ACT_NONE 0
#define ACT_ELU 1
#define ACT_LEAKY 2

template<int ACT>
__device__ __forceinline__ float apply_act(float v) {
    if constexpr (ACT == ACT_ELU)        return v > 0.f ? v : __expf(v) - 1.f;
    else if constexpr (ACT == ACT_LEAKY) return v >= 0.f ? v : NEG_SLOPE_ * v;
    else return v;
}

// read one bf16x8 fragment from swizzled row-major [row][128] storage
__device__ __forceinline__ bf16x8 frag_ld(const __bf16* src, int row, int kc) {
    return *(const bf16x8*)&src[row * D_ + ((kc ^ (row & 7)) << 3)];
}

// preload this wave's 32-col W^T strip into registers: 8 frags (32 VGPR)
__device__ __forceinline__ void load_wregs2(const __bf16* __restrict__ wmat,
                                            int wst, int ln, int lq, bf16x8 wr_[4][2]) {
#pragma unroll
    for (int ks = 0; ks < 4; ++ks)
#pragma unroll
        for (int mt = 0; mt < 2; ++mt)
            wr_[ks][mt] = frag_ld(wmat, wst * 32 + mt * 16 + ln, ks * 4 + lq);
}

// 64-row strip GEMM: lane -> out[row = nt*16+(l&15)][cols = wst*32+mt*16+lq*4 ..+3]
__device__ __forceinline__ void gemmS(const __bf16* xb, const bf16x8 wr_[4][2],
                                      int ln, int lq, f32x4 acc[2][4]) {
    const f32x4 z = {0.f, 0.f, 0.f, 0.f};
#pragma unroll
    for (int mt = 0; mt < 2; ++mt)
#pragma unroll
        for (int nt = 0; nt < 4; ++nt) acc[mt][nt] = z;
#pragma unroll
    for (int ks = 0; ks < 4; ++ks) {
        const int kc = ks * 4 + lq;
        bf16x8 b[4];
#pragma unroll
        for (int nt = 0; nt < 4; ++nt) b[nt] = frag_ld(xb, nt * 16 + ln, kc);
#pragma unroll
        for (int mt = 0; mt < 2; ++mt)
#pragma unroll
            for (int nt = 0; nt < 4; ++nt)
                acc[mt][nt] = __builtin_amdgcn_mfma_f32_16x16x32_bf16(wr_[ks][mt], b[nt], acc[mt][nt], 0, 0, 0);
    }
}

// 32-row strip GEMM
__device__ __forceinline__ void gemmS32(const __bf16* xb, const bf16x8 wr_[4][2],
                                        int ln, int lq, f32x4 acc[2][2]) {
    const f32x4 z = {0.f, 0.f, 0.f, 0.f};
#pragma unroll
    for (int mt = 0; mt < 2; ++mt) { acc[mt][0] = z; acc[mt][1] = z; }
#pragma unroll
    for (int ks = 0; ks < 4; ++ks) {
        const int kc = ks * 4 + lq;
        const bf16x8 b0 = frag_ld(xb, ln, kc);
        const bf16x8 b1 = frag_ld(xb, 16 + ln, kc);
#pragma unroll
        for (int mt = 0; mt < 2; ++mt) {
            acc[mt][0] = __builtin_amdgcn_mfma_f32_16x16x32_bf16(wr_[ks][mt], b0, acc[mt][0], 0, 0, 0);
            acc[mt][1] = __builtin_amdgcn_mfma_f32_16x16x32_bf16(wr_[ks][mt], b1, acc[mt][1], 0, 0, 0);
        }
    }
}

// 64-row epilogue -> swizzled LDS
template<int ACT>
__device__ __forceinline__ void epiS_lds(const f32x4 acc[2][4], __bf16* dst,
                                         const float* __restrict__ bias,
                                         int wst, int ln, int lq) {
#pragma unroll
    for (int mt = 0; mt < 2; ++mt) {
        const int cb = wst * 32 + mt * 16 + lq * 4;
        const f32x4 bv = *(const f32x4*)&bias[cb];
#pragma unroll
        for (int nt = 0; nt < 4; ++nt) {
            const int jr = nt * 16 + ln;
            bf16x4 o;
#pragma unroll
            for (int r = 0; r < 4; ++r)
                o[r] = (__bf16)apply_act<ACT>(acc[mt][nt][r] + bv[r]);
            *(bf16x4*)&dst[jr * D_ + (((cb >> 3) ^ (jr & 7)) << 3) + (cb & 7)] = o;
        }
    }
}

// 32-row epilogue -> swizzled LDS at row offset
template<int ACT>
__device__ __forceinline__ void epiS32_lds(const f32x4 acc[2][2], __bf16* dst, int rowoff,
                                           const float* __restrict__ bias,
                                           int wst, int ln, int lq) {
#pragma unroll
    for (int mt = 0; mt < 2; ++mt) {
        const int cb = wst * 32 + mt * 16 + lq * 4;
        const f32x4 bv = *(const f32x4*)&bias[cb];
#pragma unroll
        for (int nt = 0; nt < 2; ++nt) {
            const int jr = rowoff + nt * 16 + ln;
            bf16x4 o;
#pragma unroll
            for (int r = 0; r < 4; ++r)
                o[r] = (__bf16)apply_act<ACT>(acc[mt][nt][r] + bv[r]);
            *(bf16x4*)&dst[jr * D_ + (((cb >> 3) ^ (jr & 7)) << 3) + (cb & 7)] = o;
        }
    }
}

// prep: blocks 0-5 convert W fp32 -> WT bf16 swizzled; blocks 6-69 Sbuf + nvalid
__global__ __launch_bounds__(256) void k_prep(
    const float* __restrict__ w0, const float* __restrict__ w1,
    const float* __restrict__ w2, const float* __restrict__ w3,
    const float* __restrict__ w4, const float* __restrict__ w5,
    __bf16* __restrict__ wdst,
    const float* __restrict__ F, const int* __restrict__ STEP,
    const int* __restrict__ ENDB, const int* __restrict__ BIDX,
    float* __restrict__ Sbuf, int* __restrict__ nvalid) {
    const int t = threadIdx.x;
    if (blockIdx.x < 6) {
        const float* src;
        switch (blockIdx.x) {
            case 0: src = w0; break; case 1: src = w1; break; case 2: src = w2; break;
            case 3: src = w3; break; case 4: src = w4; break; default: src = w5; break;
        }
        __bf16* d = wdst + (size_t)blockIdx.x * D_ * D_;
        for (int id = t; id < D_ * 16; id += 256) {
            const int n = id >> 4, ch = id & 15;
            bf16x8 u;
#pragma unroll
            for (int j = 0; j < 8; ++j) u[j] = (__bf16)src[(ch * 8 + j) * D_ + n];
            *(bf16x8*)&d[n * D_ + ((ch ^ (n & 7)) << 3)] = u;
        }
        return;
    }
    const int b = blockIdx.x - 6;
    __shared__ int steps_s[J_];
    __shared__ int valid_s[J_];
    __shared__ int nv;
    const int bi = BIDX[b];
    if (t == 0) nv = 0;
    __syncthreads();
    if (t < J_) {
        const int s = STEP[bi * J_ + t];
        const int e = ENDB[bi * J_ + t];
        steps_s[t] = s;
        const int v = (s <= e) ? 1 : 0;
        valid_s[t] = v;
        if (v) atomicAdd(&nv, 1);
    }
    __syncthreads();
    if (t < D_) {
        float acc = 0.f;
        for (int j = 0; j < J_; ++j)
            if (valid_s[j]) acc += F[((size_t)b * N_ + steps_s[j]) * D_ + t];
        Sbuf[b * D_ + t] = acc;
    }
    if (t == 0) nvalid[b] = nv;
}

// fully fused, 32-output-row blocks (grid B*64). ~33.5 KB LDS -> 4 blocks/CU.
// cat: 0 = passthrough, 1 = updated (fw cand), 2 = valid head (zj z; only tile ti==0)
__global__ __launch_bounds__(256, 4) void k_fused(
    const float* __restrict__ F, const float* __restrict__ rp_,
    const __bf16* __restrict__ wsW,
    const float* __restrict__ fb1, const float* __restrict__ fb2,
    const float* __restrict__ zb1, const float* __restrict__ zb2,
    const float* __restrict__ pb1, const float* __restrict__ pb2,
    const int* __restrict__ STEP, const int* __restrict__ ENDB,
    const int* __restrict__ BIDX, const float* __restrict__ Sbuf,
    const int* __restrict__ nvalid, float* __restrict__ out) {
    __shared__ __bf16 xs[64 * D_];   // rows 0-31: x -> (cand/z) ; rows 32-63: xprev -> pr-h
    __shared__ __bf16 hs[64 * D_];   // fw h (64 rows); head reuses for mixed/zj-h
    __shared__ int stj[J_];
    __shared__ int ens[J_];
    __shared__ unsigned char cat[32];
    __shared__ float rsc_s[32];

    const int t = threadIdx.x;
    const int lane = t & 63, wst = t >> 6;
    const int ln = lane & 15, lq = lane >> 4;
    const int bid = blockIdx.x;
    const int b = bid >> 6, ti = bid & 63;
    const int r0 = ti * 32;
    const int bi = BIDX[b];
    if (t < J_) { stj[t] = STEP[bi * J_ + t]; ens[t] = ENDB[bi * J_ + t]; }
    __syncthreads();
    const float r = *rp_;
    if (t < 32) {
        const int i = r0 + t;
        const int j = i >> 6;
        const bool head = (i < J_) && (stj[i] <= ens[i]);
        const bool upd = (i > stj[j]) && (i <= ens[j]);
        const unsigned char c = head ? 2 : (upd ? 1 : 0);
        cat[t] = c;
        rsc_s[t] = (c == 1) ? __powf(r, (float)(i - stj[j])) : 0.f;
    }
    __syncthreads();

    // stage: xs rows 0-31 = x; rows 32-63 = updated ? x_prev * r^k : 0
    const float* Fb = F + (size_t)b * N_ * D_;
    for (int id = t; id < 64 * 16; id += 256) {
        const int rr = id >> 4, ch = id & 15;
        bf16x8 u;
        if (rr < 32) {
            const float* fr = Fb + (size_t)(r0 + rr) * D_ + ch * 8;
            const float4 f0 = *(const float4*)fr, f1 = *(const float4*)(fr + 4);
            u[0] = (__bf16)f0.x; u[1] = (__bf16)f0.y; u[2] = (__bf16)f0.z; u[3] = (__bf16)f0.w;
            u[4] = (__bf16)f1.x; u[5] = (__bf16)f1.y; u[6] = (__bf16)f1.z; u[7] = (__bf16)f1.w;
        } else {
            const int lr = rr - 32;
            if (cat[lr] == 1) {
                const float s = rsc_s[lr];
                const float* fr = Fb + (size_t)(r0 + lr - 1) * D_ + ch * 8;
                const float4 f0 = *(const float4*)fr, f1 = *(const float4*)(fr + 4);
                u[0] = (__bf16)(f0.x * s); u[1] = (__bf16)(f0.y * s);
                u[2] = (__bf16)(f0.z * s); u[3] = (__bf16)(f0.w * s);
                u[4] = (__bf16)(f1.x * s); u[5] = (__bf16)(f1.y * s);
                u[6] = (__bf16)(f1.z * s); u[7] = (__bf16)(f1.w * s);
            } else {
#pragma unroll
                for (int j = 0; j < 8; ++j) u[j] = (__bf16)0.f;
            }
        }
        *(bf16x8*)&xs[rr * D_ + ((ch ^ (rr & 7)) << 3)] = u;
    }
    __syncthreads();

    // fw layer 1: both branches in one 64-row GEMM -> hs
    {
        bf16x8 w1r[4][2];
        load_wregs2(wsW, wst, ln, lq, w1r);                   // fw W1^T strip
        f32x4 acc[2][4];
        gemmS(xs, w1r, ln, lq, acc);
        epiS_lds<ACT_ELU>(acc, hs, fb1, wst, ln, lq);
    }
    __syncthreads();

    // fw layer 2: chain h rows 0-31 and 32-63 -> cand, predicated into xs rows 0-31
    {
        bf16x8 w2r[4][2];
        load_wregs2(wsW + 16384, wst, ln, lq, w2r);           // fw W2^T strip
        f32x4 a2[2][2];
        const f32x4 z = {0.f, 0.f, 0.f, 0.f};
#pragma unroll
        for (int mt = 0; mt < 2; ++mt) { a2[mt][0] = z; a2[mt][1] = z; }
#pragma unroll
        for (int ks = 0; ks < 4; ++ks) {
            const int kc = ks * 4 + lq;
            const bf16x8 bl0 = frag_ld(hs, ln, kc);
            const bf16x8 bl1 = frag_ld(hs, 16 + ln, kc);
            const bf16x8 bh0 = frag_ld(hs, 32 + ln, kc);
            const bf16x8 bh1 = frag_ld(hs, 48 + ln, kc);
#pragma unroll
            for (int mt = 0; mt < 2; ++mt) {
                a2[mt][0] = __builtin_amdgcn_mfma_f32_16x16x32_bf16(w2r[ks][mt], bl0, a2[mt][0], 0, 0, 0);
                a2[mt][0] = __builtin_amdgcn_mfma_f32_16x16x32_bf16(w2r[ks][mt], bh0, a2[mt][0], 0, 0, 0);
                a2[mt][1] = __builtin_amdgcn_mfma_f32_16x16x32_bf16(w2r[ks][mt], bl1, a2[mt][1], 0, 0, 0);
                a2[mt][1] = __builtin_amdgcn_mfma_f32_16x16x32_bf16(w2r[ks][mt], bh1, a2[mt][1], 0, 0, 0);
            }
        }
#pragma unroll
        for (int nt = 0; nt < 2; ++nt) {
            const int row = nt * 16 + ln;
            if (cat[row] != 1) continue;
#pragma unroll
            for (int mt = 0; mt < 2; ++mt) {
                const int cb = wst * 32 + mt * 16 + lq * 4;
                const f32x4 bv = *(const f32x4*)&fb2[cb];
                bf16x4 o;
#pragma unroll
                for (int rr2 = 0; rr2 < 4; ++rr2)
                    o[rr2] = (__bf16)(a2[mt][nt][rr2] + 2.f * bv[rr2]);
                *(bf16x4*)&xs[row * D_ + (((cb >> 3) ^ (row & 7)) << 3) + (cb & 7)] = o;
            }
        }
    }

    // head path (tile 0 of each batch): z = MLP_zj(mixed) -> xs (predicated cat==2)
    if (ti == 0) {
        __syncthreads();   // all hs reads from fw layer 2 done
        const float n_ = (float)nvalid[b];
        const float inv = (n_ > 0.f) ? 1.f / n_ : 0.f;
        for (int id = t; id < 32 * 16; id += 256) {
            const int row = id >> 4, ch = id & 15;
            const float* cr = Fb + (size_t)stj[row] * D_ + ch * 8;
            const float4 c0 = *(const float4*)cr, c1 = *(const float4*)(cr + 4);
            const float4 s0 = *(const float4*)(Sbuf + b * D_ + ch * 8);
            const float4 s1 = *(const float4*)(Sbuf + b * D_ + ch * 8 + 4);
            bf16x8 u;
            u[0] = (__bf16)((c0.x + r * (s0.x - c0.x)) * inv);
            u[1] = (__bf16)((c0.y + r * (s0.y - c0.y)) * inv);
            u[2] = (__bf16)((c0.z + r * (s0.z - c0.z)) * inv);
            u[3] = (__bf16)((c0.w + r * (s0.w - c0.w)) * inv);
            u[4] = (__bf16)((c1.x + r * (s1.x - c1.x)) * inv);
            u[5] = (__bf16)((c1.y + r * (s1.y - c1.y)) * inv);
            u[6] = (__bf16)((c1.z + r * (s1.z - c1.z)) * inv);
            u[7] = (__bf16)((c1.w + r * (s1.w - c1.w)) * inv);
            *(bf16x8*)&hs[row * D_ + ((ch ^ (row & 7)) << 3)] = u;
        }
        __syncthreads();
        f32x4 az[2][2];
        {
            bf16x8 wza[4][2];
            load_wregs2(wsW + 4 * 16384, wst, ln, lq, wza);   // zj W1^T strip
            gemmS32(hs, wza, ln, lq, az);
            epiS32_lds<ACT_ELU>(az, hs, 32, zb1, wst, ln, lq);
        }
        __syncthreads();
        {
            bf16x8 wzb[4][2];
            load_wregs2(wsW + 5 * 16384, wst, ln, lq, wzb);   // zj W2^T strip
            gemmS32(hs + 32 * D_, wzb, ln, lq, az);
#pragma unroll
            for (int nt = 0; nt < 2; ++nt) {
                const int row = nt * 16 + ln;
                if (cat[row] != 2) continue;
#pragma unroll
                for (int mt = 0; mt < 2; ++mt) {
                    const int cb = wst * 32 + mt * 16 + lq * 4;
                    const f32x4 bv = *(const f32x4*)&zb2[cb];
                    bf16x4 o;
#pragma unroll
                    for (int rr2 = 0; rr2 < 4; ++rr2)
                        o[rr2] = (__bf16)(az[mt][nt][rr2] + bv[rr2]);
                    *(bf16x4*)&xs[row * D_ + (((cb >> 3) ^ (row & 7)) << 3) + (cb & 7)] = o;
                }
            }
        }
    }
    __syncthreads();   // xs rows 0-31 finalized (x / cand / z); xprev half dead

    // pr layer 1: xs rows 0-31 -> h into xs rows 32-63 (disjoint rows, no barrier needed)
    {
        bf16x8 p1r[4][2];
        load_wregs2(wsW + 2 * 16384, wst, ln, lq, p1r);       // pr W1^T strip
        f32x4 ap[2][2];
        gemmS32(xs, p1r, ln, lq, ap);
        epiS32_lds<ACT_ELU>(ap, xs, 32, pb1, wst, ln, lq);
    }
    __syncthreads();

    // pr layer 2: xs rows 32-63 -> out
    {
        bf16x8 p2r[4][2];
        load_wregs2(wsW + 3 * 16384, wst, ln, lq, p2r);       // pr W2^T strip
        f32x4 ap[2][2];
        gemmS32(xs + 32 * D_, p2r, ln, lq, ap);
        float* outb = out + ((size_t)b * N_ + r0) * D_;
#pragma unroll
        for (int mt = 0; mt < 2; ++mt) {
            const int cb = wst * 32 + mt * 16 + lq * 4;
            const f32x4 bv = *(const f32x4*)&pb2[cb];
#pragma unroll
            for (int nt = 0; nt < 2; ++nt) {
                const int jr = nt * 16 + ln;
                f32x4 o;
#pragma unroll
                for (int rr2 = 0; rr2 < 4; ++rr2)
                    o[rr2] = apply_act<ACT_LEAKY>(ap[mt][nt][rr2] + bv[rr2]);
                *(f32x4*)&outb[(size_t)jr * D_ + cb] = o;
            }
        }
    }
}

extern "C" void kernel_launch(void* const* d_in, const int* in_sizes, int n_in,
                              void* d_out, int out_size, void* d_ws, size_t ws_size,
                              hipStream_t stream) {
    const float* F    = (const float*)d_in[0];
    const float* rp   = (const float*)d_in[1];
    const int*  STEP  = (const int*)d_in[2];
    const int*  ENDB  = (const int*)d_in[3];
    const int*  BIDX  = (const int*)d_in[5];
    const float* fwW1 = (const float*)d_in[6];
    const float* fwb1 = (const float*)d_in[7];
    const float* fwW2 = (const float*)d_in[8];
    const float* fwb2 = (const float*)d_in[9];
    const float* zjW1 = (const float*)d_in[10];
    const float* zjb1 = (const float*)d_in[11];
    const float* zjW2 = (const float*)d_in[12];
    const float* zjb2 = (const float*)d_in[13];
    const float* prW1 = (const float*)d_in[14];
    const float* prb1 = (const float*)d_in[15];
    const float* prW2 = (const float*)d_in[16];
    const float* prb2 = (const float*)d_in[17];
    float* out = (float*)d_out;

    char* ws = (char*)d_ws;
    __bf16* wsW = (__bf16*)ws;                 // 393216 B
    float* Sbuf = (float*)(ws + 393216);       // 32768 B
    int* nvalid = (int*)(ws + 425984);         // 256 B

    hipLaunchKernelGGL(k_prep, dim3(70), dim3(256), 0, stream,
                       fwW1, fwW2, prW1, prW2, zjW1, zjW2, wsW,
                       F, STEP, ENDB, BIDX, Sbuf, nvalid);
    hipLaunchKernelGGL(k_fused, dim3(B_ * 64), dim3(256), 0, stream,
                       F, rp, wsW, fwb1, fwb2, zjb1, zjb2, prb1, prb2,
                       STEP, ENDB, BIDX, Sbuf, nvalid, out);
}